// Round 10
// baseline (268.029 us; speedup 1.0000x reference)
//
#include <hip/hip_runtime.h>

// Round 10: ABLATION. Two dispatches:
//   kan_v1_nolds : full structure minus the LDS table (register-fabricated
//                  per-interval coefficients). Output -> d_out (scratch).
//   kan_v2_full  : round-7 kernel (best so far, ~76.5us). Overwrites d_out
//                  with the correct result -> validation sees only V2.
// Per-dispatch rocprof rows separate the two; JSON dur_us ~= 229 + V1.

#define NCH 32
#define NINT 11

typedef float vf4 __attribute__((ext_vector_type(4)));

// ---------------- V1: no-LDS ablation ----------------
__global__ __launch_bounds__(256) void kan_v1_nolds(
    const float* __restrict__ x,
    const float* __restrict__ grid,
    float* __restrict__ out,
    int n4) {
  const int tid = blockIdx.x * blockDim.x + threadIdx.x;
  if (tid >= n4) return;
  const vf4* __restrict__ x4 = (const vf4*)x;
  vf4 xv = x4[tid];

  const float g0 = grid[0];
  const float inv_h = 11.0f / (grid[11] - grid[0]);

  float xs[4] = {xv.x, xv.y, xv.z, xv.w};
  float rs[4];
#pragma unroll
  for (int k = 0; k < 4; ++k) {
    float u = (xs[k] - g0) * inv_h;
    float fi = floorf(u);
    float fic = fminf(fmaxf(fi, 0.0f), 10.0f);
    float t = u - fic;
    // fabricate interval-dependent coefficients in registers (keeps the
    // floor->i dependence live, mirrors the VALU slot cost of the gather
    // without touching LDS)
    float a0 = fmaf(0.11f, fic, 0.02f);
    float a1 = fmaf(0.07f, fic, -0.01f);
    float a2 = fmaf(-0.05f, fic, 0.03f);
    float a3 = 0.01f * fic;
    float r = fmaf(fmaf(fmaf(a3, t, a2), t, a1), t, a0);
    rs[k] = (fi >= 0.0f && fi <= 10.0f) ? r : 0.0f;
  }
  vf4 ov;
  ov.x = rs[0]; ov.y = rs[1]; ov.z = rs[2]; ov.w = rs[3];
  __builtin_nontemporal_store(ov, &((vf4*)out)[tid]);
}

// ---------------- V2: real kernel (round-7 structure) ----------------
__global__ __launch_bounds__(256) void kan_v2_full(
    const float* __restrict__ x,
    const float* __restrict__ grid,
    const float* __restrict__ W,
    float* __restrict__ out,
    int n4) {
  __shared__ float4 coef[NCH * NINT + 8];  // 360 swizzled entries (~5.9 KB)

  const int tid = blockIdx.x * blockDim.x + threadIdx.x;
  const vf4* __restrict__ x4 = (const vf4*)x;

  // x-load issued first: HBM latency hides under the table build + barrier.
  vf4 xv = (tid < n4) ? x4[tid] : (vf4)(0.0f);

  const float sixth = 1.0f / 6.0f;
  for (int e = threadIdx.x; e < NCH * NINT; e += 256) {
    int c = e / NINT;
    int i = e - c * NINT;
    float w[4];
#pragma unroll
    for (int k = 0; k < 4; ++k) {
      int j = i - 3 + k;
      w[k] = (j >= 0 && j < 8) ? W[c * 8 + j] : 0.0f;
    }
    float4 a;
    a.x = (w[0] + 4.0f * w[1] + w[2]) * sixth;
    a.y = 0.5f * (w[2] - w[0]);
    a.z = 0.5f * (w[0] - 2.0f * w[1] + w[2]);
    a.w = (w[3] - w[0]) * sixth + 0.5f * (w[1] - w[2]);
    coef[e + (c >> 2)] = a;  // bank-quad swizzle: +c/4
  }
  __syncthreads();

  if (tid >= n4) return;

  const float g0 = grid[0];
  const float inv_h = 11.0f / (grid[11] - grid[0]);  // = 2.5 exactly

  const int c0 = (4 * tid) & 31;
  int base[4];
#pragma unroll
  for (int k = 0; k < 4; ++k) base[k] = (c0 + k) * NINT + (c0 >> 2);

  float xs[4] = {xv.x, xv.y, xv.z, xv.w};
  float rs[4];
#pragma unroll
  for (int k = 0; k < 4; ++k) {
    float u = (xs[k] - g0) * inv_h;
    float fi = floorf(u);
    float fic = fminf(fmaxf(fi, 0.0f), 10.0f);
    float t = u - fic;
    int i = (int)fic;
    float4 a = coef[base[k] + i];
    float r = fmaf(fmaf(fmaf(a.w, t, a.z), t, a.y), t, a.x);
    rs[k] = (fi >= 0.0f && fi <= 10.0f) ? r : 0.0f;  // half-open range mask
  }

  vf4 ov;
  ov.x = rs[0]; ov.y = rs[1]; ov.z = rs[2]; ov.w = rs[3];
  __builtin_nontemporal_store(ov, &((vf4*)out)[tid]);
}

extern "C" void kernel_launch(void* const* d_in, const int* in_sizes, int n_in,
                              void* d_out, int out_size, void* d_ws, size_t ws_size,
                              hipStream_t stream) {
  const float* x    = (const float*)d_in[0];
  const float* grid = (const float*)d_in[1];
  const float* W    = (const float*)d_in[2];
  float* out        = (float*)d_out;

  const int n  = in_sizes[0];  // 33,554,432
  const int n4 = n / 4;        // 8,388,608

  const int threads = 256;
  const int blocks  = (n4 + threads - 1) / threads;  // 32768, exact

  // Ablation dispatch (uses d_out as scratch; same-stream ordering means
  // V2 overwrites it with the correct result before validation).
  hipLaunchKernelGGL(kan_v1_nolds, dim3(blocks), dim3(threads), 0, stream,
                     x, grid, out, n4);
  // Real kernel.
  hipLaunchKernelGGL(kan_v2_full, dim3(blocks), dim3(threads), 0, stream,
                     x, grid, W, out, n4);
}

// Round 14
// 227.226 us; speedup vs baseline: 1.1796x; 1.1796x over previous
//
#include <hip/hip_runtime.h>

// B-spline (KAN) activation, order-3, uniform 12-knot grid -> 8 bases,
// per-channel Dense(1) with W[32][8].  out = a0+a1 t+a2 t^2+a3 t^3 on
// interval i (u=(x-g0)*2.5, t=u-i), coeffs from the uniform B-spline
// blending of W[c, i-3..i] (zero-padded).
//
// Round 11 (resubmitted r12, r13 after infra timeouts):
//  - Setup kernel builds the 352-entry float4 coef table ONCE into d_ws;
//    main blocks stage it with 2 coalesced loads/thread (kills the 128
//    divergent per-block-generation table builds diagnosed in r10).
//  - Conflict-free LDS indexing WITHOUT replication:
//      es(c,i) = (c>>2) + 8*((c&3)*11 + i)        (352 slots, bijective)
//    => es & 7 == c>>2 == lane&7  independent of data i: each 16-lane
//    ds_read_b128 phase group covers all 8 bank-quads exactly twice
//    (2-way = free). Removes the 7 cy/instr data-random conflicts.
//  - Flat 1 float4/thread structure (V1 ablation measured 38.5us = mem
//    floor with this structure), NT stores, x-load issued first.

#define NCH 32
#define NINT 11
#define TBL 352  // 32*11 entries

typedef float vf4 __attribute__((ext_vector_type(4)));

__global__ __launch_bounds__(256) void kan_setup(const float* __restrict__ W,
                                                 float4* __restrict__ tbl) {
  const float sixth = 1.0f / 6.0f;
  for (int e = threadIdx.x; e < TBL; e += 256) {
    int c = e / NINT;
    int i = e - c * NINT;
    float w[4];
#pragma unroll
    for (int k = 0; k < 4; ++k) {
      int j = i - 3 + k;
      w[k] = (j >= 0 && j < 8) ? W[c * 8 + j] : 0.0f;
    }
    float4 a;
    a.x = (w[0] + 4.0f * w[1] + w[2]) * sixth;
    a.y = 0.5f * (w[2] - w[0]);
    a.z = 0.5f * (w[0] - 2.0f * w[1] + w[2]);
    a.w = (w[3] - w[0]) * sixth + 0.5f * (w[1] - w[2]);
    // banked-by-channel-group index: es&7 == c>>2, unique over (c,i)
    int es = (c >> 2) + 8 * ((c & 3) * NINT + i);
    tbl[es] = a;
  }
}

__global__ __launch_bounds__(256) void kan_main(const float* __restrict__ x,
                                                const float* __restrict__ grid,
                                                const float4* __restrict__ tbl,
                                                float* __restrict__ out,
                                                int n4) {
  __shared__ float4 coef[TBL];

  const int tl = threadIdx.x;
  const int tid = blockIdx.x * blockDim.x + tl;
  const vf4* __restrict__ x4 = (const vf4*)x;

  // x-load first: HBM latency hides under table staging + barrier.
  vf4 xv = (tid < n4) ? x4[tid] : (vf4)(0.0f);

  // coalesced table stage: 2 float4 loads/thread (L2-hot), 2 ds_writes
  coef[tl] = tbl[tl];
  if (tl + 256 < TBL) coef[tl + 256] = tbl[tl + 256];
  __syncthreads();

  if (tid >= n4) return;

  const float g0 = grid[0];
  const float inv_h = 11.0f / (grid[11] - grid[0]);  // = 2.5 exactly

  // element k -> channel c = 4*(tid&7)+k; index = (tid&7) + 88k + 8i
  const int g = tid & 7;

  float xs[4] = {xv.x, xv.y, xv.z, xv.w};
  float rs[4];
#pragma unroll
  for (int k = 0; k < 4; ++k) {
    float u = (xs[k] - g0) * inv_h;
    float fi = floorf(u);
    float fic = fminf(fmaxf(fi, 0.0f), 10.0f);
    float t = u - fic;
    int i = (int)fic;
    float4 a = coef[g + 88 * k + 8 * i];
    float r = fmaf(fmaf(fmaf(a.w, t, a.z), t, a.y), t, a.x);
    rs[k] = (fi >= 0.0f && fi <= 10.0f) ? r : 0.0f;  // half-open range mask
  }

  vf4 ov;
  ov.x = rs[0]; ov.y = rs[1]; ov.z = rs[2]; ov.w = rs[3];
  __builtin_nontemporal_store(ov, &((vf4*)out)[tid]);
}

extern "C" void kernel_launch(void* const* d_in, const int* in_sizes, int n_in,
                              void* d_out, int out_size, void* d_ws, size_t ws_size,
                              hipStream_t stream) {
  const float* x    = (const float*)d_in[0];
  const float* grid = (const float*)d_in[1];
  const float* W    = (const float*)d_in[2];
  float* out        = (float*)d_out;
  float4* tbl       = (float4*)d_ws;  // 352 * 16 B = 5632 B of scratch

  const int n  = in_sizes[0];  // 33,554,432
  const int n4 = n / 4;        // 8,388,608 = 32768 * 256 exactly

  hipLaunchKernelGGL(kan_setup, dim3(1), dim3(256), 0, stream, W, tbl);

  const int threads = 256;
  const int blocks  = (n4 + threads - 1) / threads;  // 32768
  hipLaunchKernelGGL(kan_main, dim3(blocks), dim3(threads), 0, stream,
                     x, grid, tbl, out, n4);
}